// Round 2
// baseline (116.679 us; speedup 1.0000x reference)
//
#include <hip/hip_runtime.h>

// Problem constants (from reference)
#define B_SZ   256
#define L_SZ   200
#define EMBED  128
#define MAX_G  8
#define NTOK   (B_SZ * L_SZ)        // 51200 tokens
#define F2_PER_ROW (EMBED / 2)      // 64 float2 per embedding row
#define TOK_PER_BLK 4               // 4 waves/block, 1 token per wave

typedef float nativef2 __attribute__((ext_vector_type(2)));  // for nontemporal store

// ONE TOKEN PER 64-LANE WAVE. lane i owns floats [2i, 2i+1] of the 128-float
// row (8 B/lane, 512 B/wave contiguous -> fully coalesced).
//
// Why: with the token wave-uniform, readfirstlane pins t / cnt / all 8 genre
// ids into SGPRs. Control loads (seq, gcnt, tgid) become uniform single-line
// loads on the scalar path; ALL address math moves to the SALU; the masked
// weights become scalar selects feeding v_fma's SGPR operand slot. Per-thread
// VALU shrinks to the 16 FMAs + 2 adds that are the actual work. This tests
// (and fixes, if true) the "issue/VALU-overhead-bound gather" hypothesis.
__global__ __launch_bounds__(256, 8) void bert_embed_kernel(
    const int*    __restrict__ seq,       // [B,L]
    const float2* __restrict__ tok_tab,   // [VOCAB, 64] (float2 view)
    const float2* __restrict__ gen_tab,   // [21, 64]
    const float2* __restrict__ pos_tab,   // [200, 64]
    const int*    __restrict__ tgid,      // [VOCAB, 8]
    const int*    __restrict__ gcnt,      // [VOCAB]
    float2*       __restrict__ out)       // [B,L,64]
{
    const int tid  = threadIdx.x;
    const int w    = tid >> 6;           // wave id within block (0..3)
    const int lane = tid & 63;           // float2 index within row (0..63)

    const int l = blockIdx.x * TOK_PER_BLK + w;   // 0..199 (50*4 = 200, no tail)
    const int b = blockIdx.y;                     // 0..255
    const int token = b * L_SZ + l;

    // t is identical across all 64 lanes of this wave -> force into SGPR.
    const int t = __builtin_amdgcn_readfirstlane(seq[token]);

    // Big row loads: SGPR base + lane*8B offset, 512 B/wave contiguous.
    const float2 tokv = tok_tab[(long)t * F2_PER_ROW + lane];
    const float2 p    = pos_tab[l * F2_PER_ROW + lane];

    // Control loads: uniform addresses (scalar path).
    const int cnt = __builtin_amdgcn_readfirstlane(gcnt[t]);   // in [1, 8]

    // 8 genre ids = 32B contiguous, always-valid memory (table is [VOCAB][8]).
    const int4* g4 = (const int4*)(tgid + (long)t * MAX_G);
    const int4  ga = g4[0];
    const int4  gb = g4[1];
    const int g0 = __builtin_amdgcn_readfirstlane(ga.x);
    const int g1 = __builtin_amdgcn_readfirstlane(ga.y);
    const int g2 = __builtin_amdgcn_readfirstlane(ga.z);
    const int g3 = __builtin_amdgcn_readfirstlane(ga.w);
    const int g4i = __builtin_amdgcn_readfirstlane(gb.x);
    const int g5 = __builtin_amdgcn_readfirstlane(gb.y);
    const int g6 = __builtin_amdgcn_readfirstlane(gb.z);
    const int g7 = __builtin_amdgcn_readfirstlane(gb.w);

    // 8 genre-row loads, SGPR base + lane*8 (10.75 KB table, L1/L2-hot).
    const float2 r0 = gen_tab[g0  * F2_PER_ROW + lane];
    const float2 r1 = gen_tab[g1  * F2_PER_ROW + lane];
    const float2 r2 = gen_tab[g2  * F2_PER_ROW + lane];
    const float2 r3 = gen_tab[g3  * F2_PER_ROW + lane];
    const float2 r4 = gen_tab[g4i * F2_PER_ROW + lane];
    const float2 r5 = gen_tab[g5  * F2_PER_ROW + lane];
    const float2 r6 = gen_tab[g6  * F2_PER_ROW + lane];
    const float2 r7 = gen_tab[g7  * F2_PER_ROW + lane];

    // Masked mean weights: cnt is scalar -> scalar compares + cselect.
    const float inv = 1.0f / (float)cnt;
    const float w0 = inv;                         // cnt >= 1 always
    const float w1 = (1 < cnt) ? inv : 0.0f;
    const float w2 = (2 < cnt) ? inv : 0.0f;
    const float w3 = (3 < cnt) ? inv : 0.0f;
    const float w4 = (4 < cnt) ? inv : 0.0f;
    const float w5 = (5 < cnt) ? inv : 0.0f;
    const float w6 = (6 < cnt) ? inv : 0.0f;
    const float w7 = (7 < cnt) ? inv : 0.0f;

    nativef2 acc;
    acc.x = tokv.x + p.x;
    acc.y = tokv.y + p.y;
    acc.x = fmaf(w0, r0.x, acc.x); acc.y = fmaf(w0, r0.y, acc.y);
    acc.x = fmaf(w1, r1.x, acc.x); acc.y = fmaf(w1, r1.y, acc.y);
    acc.x = fmaf(w2, r2.x, acc.x); acc.y = fmaf(w2, r2.y, acc.y);
    acc.x = fmaf(w3, r3.x, acc.x); acc.y = fmaf(w3, r3.y, acc.y);
    acc.x = fmaf(w4, r4.x, acc.x); acc.y = fmaf(w4, r4.y, acc.y);
    acc.x = fmaf(w5, r5.x, acc.x); acc.y = fmaf(w5, r5.y, acc.y);
    acc.x = fmaf(w6, r6.x, acc.x); acc.y = fmaf(w6, r6.y, acc.y);
    acc.x = fmaf(w7, r7.x, acc.x); acc.y = fmaf(w7, r7.y, acc.y);

    // Nontemporal store: output has zero reuse; keep L2/L3 for the gathers.
    nativef2* dst = (nativef2*)&out[(long)token * F2_PER_ROW + lane];
    __builtin_nontemporal_store(acc, dst);
}

extern "C" void kernel_launch(void* const* d_in, const int* in_sizes, int n_in,
                              void* d_out, int out_size, void* d_ws, size_t ws_size,
                              hipStream_t stream) {
    const int*    seq     = (const int*)   d_in[0];  // sequence (256,200) int32
    const float2* tok_tab = (const float2*)d_in[1];  // token_table (100000,128) f32
    const float2* gen_tab = (const float2*)d_in[2];  // genre_table (21,128) f32
    const float2* pos_tab = (const float2*)d_in[3];  // pos_table (200,128) f32
    const int*    tgid    = (const int*)   d_in[4];  // token_genre_ids (100000,8)
    const int*    gcnt    = (const int*)   d_in[5];  // genre_counts (100000,)
    float2*       out     = (float2*)      d_out;    // (256,200,128) f32

    dim3 grid(L_SZ / TOK_PER_BLK, B_SZ);  // (50, 256) = 12800 blocks, no tail
    bert_embed_kernel<<<grid, 256, 0, stream>>>(seq, tok_tab, gen_tab,
                                                pos_tab, tgid, gcnt, out);
}

// Round 3
// 111.469 us; speedup vs baseline: 1.0467x; 1.0467x over previous
//
#include <hip/hip_runtime.h>

// Problem constants (from reference)
#define B_SZ   256
#define L_SZ   200
#define EMBED  128
#define MAX_G  8
#define NTOK   (B_SZ * L_SZ)        // 51200 tokens
#define F4_PER_ROW (EMBED / 4)      // 32 float4 per embedding row
#define TOK_PER_BLK 8               // 8 tokens per 256-thread block

typedef float nativef4 __attribute__((ext_vector_type(4)));  // for nontemporal store

// Champion structure (R0, 111.3 us): 32 lanes per token, each lane owns one
// float4 (16 B) of the 128-float row -> dwordx4 loads/stores, 2 tokens/wave.
// R1 (occupancy pin) and R2 (wave-uniform scalarization, float2) proved the
// kernel is neither occupancy- nor VALU-issue-bound and that 16 B/lane VMEM
// width matters. This round: R0 + free cleanups only — 2D grid removes the
// %200 magic-mul and the tail branch.
__global__ __launch_bounds__(256) void bert_embed_kernel(
    const int*    __restrict__ seq,       // [B,L]
    const float4* __restrict__ tok_tab,   // [VOCAB, 32] (float4 view)
    const float4* __restrict__ gen_tab,   // [21, 32]
    const float4* __restrict__ pos_tab,   // [200, 32]
    const int*    __restrict__ tgid,      // [VOCAB, 8]
    const int*    __restrict__ gcnt,      // [VOCAB]
    float4*       __restrict__ out)       // [B,L,32]
{
    const int tid   = threadIdx.x;
    const int group = tid >> 5;          // token slot within block (0..7)
    const int lane  = tid & 31;          // float4 index within row (0..31)

    const int l = blockIdx.x * TOK_PER_BLK + group;  // 0..199 (25*8, no tail)
    const int b = blockIdx.y;                        // 0..255
    const int token_idx = b * L_SZ + l;

    const int t = seq[token_idx];

    // Issue all independent loads up front: token row, pos row, count, gids.
    const float4 tokv = tok_tab[(long)t * F4_PER_ROW + lane];
    const float4 p    = pos_tab[l * F4_PER_ROW + lane];
    const int    cnt  = gcnt[t];

    // 8 genre ids = 32B contiguous, always-valid memory (table is [VOCAB][8]).
    const int4* g4 = (const int4*)(tgid + (long)t * MAX_G);
    const int4  ga = g4[0];
    const int4  gb = g4[1];
    const int gid[MAX_G] = { ga.x, ga.y, ga.z, ga.w, gb.x, gb.y, gb.z, gb.w };

    // Issue all 8 genre-row loads independently (tiny 10.75KB table, cache-hot).
    float4 r[MAX_G];
    #pragma unroll
    for (int i = 0; i < MAX_G; ++i)
        r[i] = gen_tab[gid[i] * F4_PER_ROW + lane];

    // Masked mean: weight inv for i<cnt, 0 otherwise.
    const float inv = 1.0f / (float)cnt;
    nativef4 acc;
    acc.x = tokv.x + p.x;
    acc.y = tokv.y + p.y;
    acc.z = tokv.z + p.z;
    acc.w = tokv.w + p.w;
    #pragma unroll
    for (int i = 0; i < MAX_G; ++i) {
        const float w = (i < cnt) ? inv : 0.0f;
        acc.x = fmaf(w, r[i].x, acc.x);
        acc.y = fmaf(w, r[i].y, acc.y);
        acc.z = fmaf(w, r[i].z, acc.z);
        acc.w = fmaf(w, r[i].w, acc.w);
    }

    // Nontemporal store: output has zero reuse; keep L2/L3 for the gathers.
    nativef4* dst = (nativef4*)&out[(long)token_idx * F4_PER_ROW + lane];
    __builtin_nontemporal_store(acc, dst);
}

extern "C" void kernel_launch(void* const* d_in, const int* in_sizes, int n_in,
                              void* d_out, int out_size, void* d_ws, size_t ws_size,
                              hipStream_t stream) {
    const int*    seq     = (const int*)   d_in[0];  // sequence (256,200) int32
    const float4* tok_tab = (const float4*)d_in[1];  // token_table (100000,128) f32
    const float4* gen_tab = (const float4*)d_in[2];  // genre_table (21,128) f32
    const float4* pos_tab = (const float4*)d_in[3];  // pos_table (200,128) f32
    const int*    tgid    = (const int*)   d_in[4];  // token_genre_ids (100000,8)
    const int*    gcnt    = (const int*)   d_in[5];  // genre_counts (100000,)
    float4*       out     = (float4*)      d_out;    // (256,200,128) f32

    dim3 grid(L_SZ / TOK_PER_BLK, B_SZ);  // (25, 256) = 6400 blocks, exact
    bert_embed_kernel<<<grid, 256, 0, stream>>>(seq, tok_tab, gen_tab,
                                                pos_tab, tgid, gcnt, out);
}